// Round 1
// baseline (138.395 us; speedup 1.0000x reference)
//
#include <hip/hip_runtime.h>
#include <hip/hip_bf16.h>

// ---------- types ----------
typedef __attribute__((ext_vector_type(8))) short bf16x8;   // 4 VGPR MFMA A/B frag
typedef __attribute__((ext_vector_type(4))) float f32x4;    // 4 VGPR MFMA C/D frag
typedef __attribute__((ext_vector_type(4))) unsigned int uint4v;

__device__ __forceinline__ unsigned short f2bf(float f) {
    __hip_bfloat16 h = __float2bfloat16(f);   // RNE
    return __builtin_bit_cast(unsigned short, h);
}

// Problem constants: B=16, C=768, H=W=48 -> HW=2304, tokens/mod = 36864
// D1 = 192, modalities M = 3.
#define BT 128            // tokens per block
#define TPM 288           // tiles per modality = 36864/128
#define NCHUNK 24         // 768 / 32

// ---------- precompute: partial u/v sums (u = g.W1 col-sums, v = b.W1) ----------
__global__ void prep_partial(const float* __restrict__ w1, const float* __restrict__ lng,
                             const float* __restrict__ lnb,
                             float* __restrict__ upart, float* __restrict__ vpart)
{
    const int m   = blockIdx.x >> 3;
    const int seg = blockIdx.x & 7;
    const int d   = threadIdx.x;          // 192 threads
    const float* w1m = w1 + (size_t)m * 768 * 192;
    const float* gm  = lng + m * 768;
    const float* bm  = lnb + m * 768;
    const int c0 = seg * 96;
    float su = 0.f, sv = 0.f;
    for (int c = 0; c < 96; ++c) {
        float wv = w1m[(size_t)(c0 + c) * 192 + d];
        su += gm[c0 + c] * wv;
        sv += bm[c0 + c] * wv;
    }
    upart[(m * 8 + seg) * 192 + d] = su;
    vpart[(m * 8 + seg) * 192 + d] = sv;
}

__global__ void prep_combine(const float* __restrict__ upart, const float* __restrict__ vpart,
                             const float* __restrict__ b1,
                             float* __restrict__ u, float* __restrict__ vb)
{
    const int m = blockIdx.x;
    const int d = threadIdx.x;            // 192 threads
    float su = 0.f, sv = 0.f;
    for (int s = 0; s < 8; ++s) {
        su += upart[(m * 8 + s) * 192 + d];
        sv += vpart[(m * 8 + s) * 192 + d];
    }
    u[m * 192 + d]  = su;
    vb[m * 192 + d] = sv + b1[m * 192 + d];
}

// ---------- precompute: pack g*W1 as bf16 in MFMA B-fragment order ----------
// Layout: w1f[m][kk(24)][nf(12)][lane(64)][8], where for 16x16x32 bf16:
//   B-frag lane l holds B[k = (l>>4)*8 + j][n = l&15], j = 0..7 contiguous.
__global__ void prep_pack(const float* __restrict__ w1, const float* __restrict__ lng,
                          unsigned short* __restrict__ w1f)
{
    const int m  = blockIdx.x / 24;
    const int kk = blockIdx.x % 24;
    const int tid = threadIdx.x;          // 256 threads
    __shared__ float ws[32 * 192];
    const float* w1m = w1 + ((size_t)m * 768 + kk * 32) * 192;
    const float* gm  = lng + m * 768 + kk * 32;
    for (int i = tid; i < 6144; i += 256) {
        int cl = i / 192, d = i % 192;
        ws[i] = gm[cl] * w1m[(size_t)cl * 192 + d];
    }
    __syncthreads();
    unsigned short* outp = w1f + ((size_t)m * 24 + kk) * 6144;
    for (int i = tid; i < 6144; i += 256) {
        int nf   = i >> 9;
        int rem  = i & 511;
        int lane = rem >> 3;
        int j    = rem & 7;
        int cl   = ((lane >> 4) << 3) + j;        // k within 32-chunk
        int d    = (nf << 4) + (lane & 15);       // n
        outp[i]  = f2bf(ws[cl * 192 + d]);
    }
}

// ---------- fused main kernel ----------
// Block: 256 thr (4 waves), 128 tokens, K streamed in 24 chunks of 32 ch.
// Wave (wm = w>>1, wn = w&1) owns tokens [wm*64, wm*64+64) x dims [wn*96, wn*96+96).
__global__ __launch_bounds__(256, 2)
void fused_main(const float* __restrict__ f0, const float* __restrict__ f1,
                const float* __restrict__ f2,
                const unsigned short* __restrict__ w1f,
                const float* __restrict__ u_g, const float* __restrict__ vb_g,
                const float* __restrict__ w2_g, const float* __restrict__ b2_g,
                float* __restrict__ out)
{
    const int bx   = blockIdx.x;
    const int mod  = bx / TPM;
    const int tile = bx % TPM;
    const float* feat = (mod == 0) ? f0 : ((mod == 1) ? f1 : f2);
    const int T0   = tile * BT;               // global token index (b*2304 + hw)
    const int bimg = T0 / 2304;
    const int hw0  = T0 % 2304;
    const float* fbase = feat + (size_t)bimg * 768 * 2304 + hw0;

    const int tid = threadIdx.x;
    const int l   = tid & 63;
    const int w   = tid >> 6;
    const int tp  = l;        // token pair: rows 2*tp, 2*tp+1
    const int g   = w;        // this wave's 8-channel group within each 32-ch chunk

    // A tile: [token][40 bf16] (80 B rows, 16B-aligned slots, slot-XOR swizzle)
    __shared__ unsigned short Alds[128][40];
    __shared__ unsigned short Blds[12 * 512];   // one 32ch x 192d chunk in frag order
    __shared__ float redS[4][128];
    __shared__ float redQ[4][128];
    __shared__ float mu_s[128], rs_s[128];
    __shared__ float red2[2][128];

    const unsigned short* w1fm = w1f + (size_t)mod * 24 * 6144;

    f32x4 acc[4][6];
    #pragma unroll
    for (int a = 0; a < 4; ++a)
        #pragma unroll
        for (int b = 0; b < 6; ++b) acc[a][b] = (f32x4){0.f, 0.f, 0.f, 0.f};

    float sum0 = 0.f, ssq0 = 0.f, sum1 = 0.f, ssq1 = 0.f;

    float2 avA[8], avB[8];
    uint4v brA[3], brB[3];

    auto LOADC = [&](float2 (&av)[8], uint4v (&br)[3], int kk) {
        const float* sA = fbase + (size_t)(kk * 32 + g * 8) * 2304 + 2 * tp;
        #pragma unroll
        for (int j = 0; j < 8; ++j)
            av[j] = *reinterpret_cast<const float2*>(sA + (size_t)j * 2304);
        const uint4v* sB = reinterpret_cast<const uint4v*>(w1fm + (size_t)kk * 6144);
        #pragma unroll
        for (int i = 0; i < 3; ++i)
            br[i] = sB[i * 256 + tid];
    };

    auto STEP = [&](float2 (&av)[8], uint4v (&br)[3],
                    float2 (&avn)[8], uint4v (&brn)[3], int kk) {
        __syncthreads();                      // (a) prev MFMA done with LDS
        // ---- stats + pack + A write (reg-staged transpose) ----
        const int t0 = 2 * tp, t1 = t0 + 1;
        const int s0 = g ^ (((t0 >> 2) ^ (t0 >> 4)) & 3);
        const int s1 = g ^ (((t1 >> 2) ^ (t1 >> 4)) & 3);
        bf16x8 p0, p1;
        #pragma unroll
        for (int j = 0; j < 8; ++j) {
            float x0 = av[j].x, x1 = av[j].y;
            p0[j] = (short)f2bf(x0);
            p1[j] = (short)f2bf(x1);
            sum0 += x0; ssq0 += x0 * x0;
            sum1 += x1; ssq1 += x1 * x1;
        }
        *reinterpret_cast<bf16x8*>(&Alds[t0][s0 * 8]) = p0;
        *reinterpret_cast<bf16x8*>(&Alds[t1][s1 * 8]) = p1;
        #pragma unroll
        for (int i = 0; i < 3; ++i)
            *reinterpret_cast<uint4v*>(&Blds[(i * 256 + tid) * 8]) = br[i];
        __syncthreads();                      // (b) tile visible
        if (kk + 1 < NCHUNK) LOADC(avn, brn, kk + 1);   // prefetch flies over MFMA
        // ---- fragments + MFMA ----
        const int col = l & 15, lg = l >> 4;
        const int wm = w >> 1, wn = w & 1;
        bf16x8 af[4];
        #pragma unroll
        for (int mf = 0; mf < 4; ++mf) {
            int t = wm * 64 + mf * 16 + col;
            int s = lg ^ (((t >> 2) ^ (t >> 4)) & 3);
            af[mf] = *reinterpret_cast<const bf16x8*>(&Alds[t][s * 8]);
        }
        bf16x8 bfr[6];
        #pragma unroll
        for (int nf = 0; nf < 6; ++nf)
            bfr[nf] = *reinterpret_cast<const bf16x8*>(&Blds[((wn * 6 + nf) * 64 + l) * 8]);
        #pragma unroll
        for (int mf = 0; mf < 4; ++mf)
            #pragma unroll
            for (int nf = 0; nf < 6; ++nf)
                acc[mf][nf] = __builtin_amdgcn_mfma_f32_16x16x32_bf16(
                                  af[mf], bfr[nf], acc[mf][nf], 0, 0, 0);
    };

    LOADC(avA, brA, 0);
    #pragma unroll 1
    for (int kt = 0; kt < NCHUNK / 2; ++kt) {
        STEP(avA, brA, avB, brB, 2 * kt);
        STEP(avB, brB, avA, brA, 2 * kt + 1);
    }

    // ---- LayerNorm stats ----
    redS[g][2 * tp] = sum0;  redS[g][2 * tp + 1] = sum1;
    redQ[g][2 * tp] = ssq0;  redQ[g][2 * tp + 1] = ssq1;
    __syncthreads();
    if (tid < 128) {
        float S = redS[0][tid] + redS[1][tid] + redS[2][tid] + redS[3][tid];
        float Q = redQ[0][tid] + redQ[1][tid] + redQ[2][tid] + redQ[3][tid];
        float mu = S * (1.f / 768.f);
        float var = Q * (1.f / 768.f) - mu * mu;
        mu_s[tid] = mu;
        rs_s[tid] = rsqrtf(var + 1e-5f);
    }
    __syncthreads();

    // ---- epilogue: affine LN fix + GELU + dot(w2) + sigmoid ----
    const int col = l & 15, lg = l >> 4;
    const int wm = w >> 1, wn = w & 1;
    const float* um  = u_g  + mod * 192;
    const float* vbm = vb_g + mod * 192;
    const float* w2m = w2_g + mod * 192;
    float uf[6], vbf[6], w2f[6];
    #pragma unroll
    for (int nf = 0; nf < 6; ++nf) {
        int d = wn * 96 + nf * 16 + col;
        uf[nf] = um[d]; vbf[nf] = vbm[d]; w2f[nf] = w2m[d];
    }
    float ps[4][4];
    #pragma unroll
    for (int mf = 0; mf < 4; ++mf) {
        #pragma unroll
        for (int r = 0; r < 4; ++r) {
            int t = wm * 64 + mf * 16 + lg * 4 + r;   // C/D: row=(lane>>4)*4+reg
            float mu = mu_s[t], rs = rs_s[t];
            float p = 0.f;
            #pragma unroll
            for (int nf = 0; nf < 6; ++nf) {
                float x = rs * (acc[mf][nf][r] - mu * uf[nf]) + vbf[nf];
                float h = 0.5f * x * (1.f + erff(x * 0.70710678118f));  // exact GELU
                p += h * w2f[nf];
            }
            ps[mf][r] = p;
        }
    }
    #pragma unroll
    for (int m = 1; m < 16; m <<= 1)
        #pragma unroll
        for (int mf = 0; mf < 4; ++mf)
            #pragma unroll
            for (int r = 0; r < 4; ++r)
                ps[mf][r] += __shfl_xor(ps[mf][r], m, 64);
    if (col == 0) {
        #pragma unroll
        for (int mf = 0; mf < 4; ++mf)
            #pragma unroll
            for (int r = 0; r < 4; ++r)
                red2[wn][wm * 64 + mf * 16 + lg * 4 + r] = ps[mf][r];
    }
    __syncthreads();
    if (tid < 128) {
        float logit = red2[0][tid] + red2[1][tid] + b2_g[mod];
        out[(size_t)mod * 36864 + T0 + tid] = 1.f / (1.f + expf(-logit));
    }
}

// ---------- launch ----------
extern "C" void kernel_launch(void* const* d_in, const int* in_sizes, int n_in,
                              void* d_out, int out_size, void* d_ws, size_t ws_size,
                              hipStream_t stream)
{
    const float* f0  = (const float*)d_in[0];
    const float* f1  = (const float*)d_in[1];
    const float* f2  = (const float*)d_in[2];
    const float* lng = (const float*)d_in[3];
    const float* lnb = (const float*)d_in[4];
    const float* w1  = (const float*)d_in[5];
    const float* b1  = (const float*)d_in[6];
    const float* w2  = (const float*)d_in[7];
    const float* b2  = (const float*)d_in[8];
    float* out = (float*)d_out;

    char* ws = (char*)d_ws;
    unsigned short* w1f = (unsigned short*)ws;          // 884736 B
    float* u     = (float*)(ws + 884736);               // 2304 B
    float* vb    = (float*)(ws + 887040);               // 2304 B
    float* upart = (float*)(ws + 889344);               // 18432 B
    float* vpart = (float*)(ws + 907776);               // 18432 B (total ~926 KB)

    prep_partial<<<dim3(24), dim3(192), 0, stream>>>(w1, lng, lnb, upart, vpart);
    prep_combine<<<dim3(3),  dim3(192), 0, stream>>>(upart, vpart, b1, u, vb);
    prep_pack   <<<dim3(72), dim3(256), 0, stream>>>(w1, lng, w1f);
    fused_main  <<<dim3(3 * TPM), dim3(256), 0, stream>>>(f0, f1, f2, w1f, u, vb, w2, b2, out);
}

// Round 2
// 106.113 us; speedup vs baseline: 1.3042x; 1.3042x over previous
//
#include <hip/hip_runtime.h>
#include <hip/hip_bf16.h>

// ---------- types ----------
typedef __attribute__((ext_vector_type(8))) short bf16x8;   // 4 VGPR MFMA A/B frag
typedef __attribute__((ext_vector_type(4))) short bf16x4;   // 8B packed store
typedef __attribute__((ext_vector_type(4))) float f32x4;    // 4 VGPR MFMA C/D frag

__device__ __forceinline__ unsigned short f2bf(float f) {
    __hip_bfloat16 h = __float2bfloat16(f);   // RNE
    return __builtin_bit_cast(unsigned short, h);
}

// Problem constants: B=16, C=768, H=W=48 -> HW=2304, tokens/mod = 36864
// D1 = 192, modalities M = 3.
#define BT 64             // tokens per block
#define TPM 576           // tiles per modality = 36864/64
#define NCHUNK 24         // 768 / 32

// ---------- precompute: partial u/v sums (u = g.W1 col-sums, v = b.W1) ----------
__global__ void prep_partial(const float* __restrict__ w1, const float* __restrict__ lng,
                             const float* __restrict__ lnb,
                             float* __restrict__ upart, float* __restrict__ vpart)
{
    const int m   = blockIdx.x >> 3;
    const int seg = blockIdx.x & 7;
    const int d   = threadIdx.x;          // 192 threads
    const float* w1m = w1 + (size_t)m * 768 * 192;
    const float* gm  = lng + m * 768;
    const float* bm  = lnb + m * 768;
    const int c0 = seg * 96;
    float su = 0.f, sv = 0.f;
    for (int c = 0; c < 96; ++c) {
        float wv = w1m[(size_t)(c0 + c) * 192 + d];
        su += gm[c0 + c] * wv;
        sv += bm[c0 + c] * wv;
    }
    upart[(m * 8 + seg) * 192 + d] = su;
    vpart[(m * 8 + seg) * 192 + d] = sv;
}

__global__ void prep_combine(const float* __restrict__ upart, const float* __restrict__ vpart,
                             const float* __restrict__ b1,
                             float* __restrict__ u, float* __restrict__ vb)
{
    const int m = blockIdx.x;
    const int d = threadIdx.x;            // 192 threads
    float su = 0.f, sv = 0.f;
    for (int s = 0; s < 8; ++s) {
        su += upart[(m * 8 + s) * 192 + d];
        sv += vpart[(m * 8 + s) * 192 + d];
    }
    u[m * 192 + d]  = su;
    vb[m * 192 + d] = sv + b1[m * 192 + d];
}

// ---------- precompute: pack g*W1 as bf16 in MFMA B-fragment order ----------
// Layout: w1f[m][kk(24)][nf(12)][lane(64)][8], where for 16x16x32 bf16:
//   B-frag lane l holds B[k = (l>>4)*8 + j][n = l&15], j = 0..7 contiguous.
__global__ void prep_pack(const float* __restrict__ w1, const float* __restrict__ lng,
                          unsigned short* __restrict__ w1f)
{
    const int m  = blockIdx.x / 24;
    const int kk = blockIdx.x % 24;
    const int tid = threadIdx.x;          // 256 threads
    __shared__ float ws[32 * 192];
    const float* w1m = w1 + ((size_t)m * 768 + kk * 32) * 192;
    const float* gm  = lng + m * 768 + kk * 32;
    for (int i = tid; i < 6144; i += 256) {
        int cl = i / 192, d = i % 192;
        ws[i] = gm[cl] * w1m[(size_t)cl * 192 + d];
    }
    __syncthreads();
    unsigned short* outp = w1f + ((size_t)m * 24 + kk) * 6144;
    for (int i = tid; i < 6144; i += 256) {
        int nf   = i >> 9;
        int rem  = i & 511;
        int lane = rem >> 3;
        int j    = rem & 7;
        int cl   = ((lane >> 4) << 3) + j;        // k within 32-chunk
        int d    = (nf << 4) + (lane & 15);       // n
        outp[i]  = f2bf(ws[cl * 192 + d]);
    }
}

// ---------- fused main kernel ----------
// Block: 256 thr (4 waves), 64 tokens. Each wave w owns the d-slice
// [w*48, w*48+48) (3 MFMA n-frags) over ALL 64 tokens (4 m-frags).
// K streamed in 24 chunks of 32 ch; wave w loads channels [w*8, w*8+8).
//
// K-loop sync: ONE raw s_barrier per step (no vmcnt drain!), LDS A-tile
// double-buffered. Safety: pack(k+1) writes buf^1 (disjoint from mfma(k)'s
// buf); pack(k+2) rewrites buf, but every wave's ds_reads of buf completed
// before its own mfma(k) issue (compiler lgkmcnt wait), which precedes its
// barrier(k+1) arrival, which precedes any wave's pack(k+2). Global-load
// prefetches (A depth-2 regs, B depth-2 regs from L2-resident w1f) stay in
// flight across the raw barriers -> counted vmcnt waits (T4).
__global__ __launch_bounds__(256, 3)
void fused_main(const float* __restrict__ f0, const float* __restrict__ f1,
                const float* __restrict__ f2,
                const unsigned short* __restrict__ w1f,
                const float* __restrict__ u_g, const float* __restrict__ vb_g,
                const float* __restrict__ w2_g, const float* __restrict__ b2_g,
                float* __restrict__ out)
{
    const int bx   = blockIdx.x;
    const int mod  = bx / TPM;
    const int tile = bx % TPM;
    const float* feat = (mod == 0) ? f0 : ((mod == 1) ? f1 : f2);
    const int T0   = tile * BT;               // global token index (b*2304 + hw)
    const int bimg = T0 / 2304;
    const int hw0  = T0 % 2304;               // 64 | 2304, no image crossing
    const float* fbase = feat + (size_t)bimg * 768 * 2304 + hw0;

    const int tid = threadIdx.x;
    const int l   = tid & 63;
    const int w   = tid >> 6;     // wave 0..3
    const int p   = l & 31;       // token pair: rows 2p, 2p+1
    const int cg  = l >> 5;       // which 4-ch half of this wave's 8-ch slot

    __shared__ unsigned short Atile[2][64][40];  // 16B slots, XOR-swizzled
    __shared__ float redS[4][64], redQ[4][64];
    __shared__ float mu_s[64], rs_s[64];
    __shared__ float red2[4][64];

    const unsigned short* w1fm = w1f + (size_t)mod * 24 * 6144;

    f32x4 acc[4][3];
    #pragma unroll
    for (int a = 0; a < 4; ++a)
        #pragma unroll
        for (int b = 0; b < 3; ++b) acc[a][b] = (f32x4){0.f, 0.f, 0.f, 0.f};

    float sum0 = 0.f, ssq0 = 0.f, sum1 = 0.f, ssq1 = 0.f;

    float2 avA[4], avB[4];
    bf16x8 bfA[3], bfB[3];

    auto LOADA = [&](float2 (&av)[4], int kk) {
        const float* sA = fbase + (size_t)(kk * 32 + w * 8 + cg * 4) * 2304 + 2 * p;
        #pragma unroll
        for (int j = 0; j < 4; ++j)
            av[j] = *reinterpret_cast<const float2*>(sA + (size_t)j * 2304);
    };
    auto LOADB = [&](bf16x8 (&bf)[3], int kk) {
        const bf16x8* sB = reinterpret_cast<const bf16x8*>(w1fm + (size_t)kk * 6144);
        #pragma unroll
        for (int nf = 0; nf < 3; ++nf)
            bf[nf] = sB[(w * 3 + nf) * 64 + l];      // 16B/lane, coalesced, L2-hit
    };

    auto STEP = [&](float2 (&av)[4], bf16x8 (&bf)[3], int kk) {
        const int buf = kk & 1;
        // ---- stats + pack + A write (compiler inserts counted vmcnt for av) ----
        const int t0 = 2 * p, t1 = t0 + 1;
        const int s0 = w ^ (((t0 >> 2) ^ (t0 >> 4)) & 3);
        const int s1 = w ^ (((t1 >> 2) ^ (t1 >> 4)) & 3);
        bf16x4 q0, q1;
        #pragma unroll
        for (int j = 0; j < 4; ++j) {
            float x0 = av[j].x, x1 = av[j].y;
            q0[j] = (short)f2bf(x0);
            q1[j] = (short)f2bf(x1);
            sum0 += x0; ssq0 += x0 * x0;
            sum1 += x1; ssq1 += x1 * x1;
        }
        *reinterpret_cast<bf16x4*>(&Atile[buf][t0][s0 * 8 + cg * 4]) = q0;
        *reinterpret_cast<bf16x4*>(&Atile[buf][t1][s1 * 8 + cg * 4]) = q1;
        // ---- prefetch A two steps ahead into just-freed regs ----
        int kn = kk + 2; if (kn > NCHUNK - 1) kn = NCHUNK - 1;
        LOADA(av, kn);
        // ---- raw barrier: LDS visible, global loads stay in flight ----
        asm volatile("s_waitcnt lgkmcnt(0)" ::: "memory");
        __builtin_amdgcn_sched_barrier(0);
        __builtin_amdgcn_s_barrier();
        // ---- fragments + MFMA ----
        const int col = l & 15, lg = l >> 4;
        #pragma unroll
        for (int mf = 0; mf < 4; ++mf) {
            int t = mf * 16 + col;
            int s = lg ^ (((t >> 2) ^ (t >> 4)) & 3);
            bf16x8 af = *reinterpret_cast<const bf16x8*>(&Atile[buf][t][s * 8]);
            #pragma unroll
            for (int nf = 0; nf < 3; ++nf)
                acc[mf][nf] = __builtin_amdgcn_mfma_f32_16x16x32_bf16(
                                  af, bf[nf], acc[mf][nf], 0, 0, 0);
        }
        // ---- prefetch B two steps ahead (regs just consumed by MFMA) ----
        LOADB(bf, kn);
    };

    LOADA(avA, 0); LOADB(bfA, 0);
    LOADA(avB, 1); LOADB(bfB, 1);
    #pragma unroll 1
    for (int kt = 0; kt < NCHUNK / 2; ++kt) {
        STEP(avA, bfA, 2 * kt);
        STEP(avB, bfB, 2 * kt + 1);
    }

    // ---- LayerNorm stats (per token over all 768 ch) ----
    sum0 += __shfl_xor(sum0, 32);  sum1 += __shfl_xor(sum1, 32);
    ssq0 += __shfl_xor(ssq0, 32);  ssq1 += __shfl_xor(ssq1, 32);
    if (l < 32) {
        redS[w][2 * p] = sum0;  redS[w][2 * p + 1] = sum1;
        redQ[w][2 * p] = ssq0;  redQ[w][2 * p + 1] = ssq1;
    }
    __syncthreads();
    if (tid < 64) {
        float S = redS[0][tid] + redS[1][tid] + redS[2][tid] + redS[3][tid];
        float Q = redQ[0][tid] + redQ[1][tid] + redQ[2][tid] + redQ[3][tid];
        float mu = S * (1.f / 768.f);
        float var = Q * (1.f / 768.f) - mu * mu;
        mu_s[tid] = mu;
        rs_s[tid] = rsqrtf(var + 1e-5f);
    }
    __syncthreads();

    // ---- epilogue: affine LN fix + GELU + dot(w2) + sigmoid ----
    const int col = l & 15, lg = l >> 4;
    const float* um  = u_g  + mod * 192;
    const float* vbm = vb_g + mod * 192;
    const float* w2m = w2_g + mod * 192;
    float uf[3], vbf[3], w2f[3];
    #pragma unroll
    for (int nf = 0; nf < 3; ++nf) {
        int d = (w * 3 + nf) * 16 + col;
        uf[nf] = um[d]; vbf[nf] = vbm[d]; w2f[nf] = w2m[d];
    }
    float ps[4][4];
    #pragma unroll
    for (int mf = 0; mf < 4; ++mf) {
        #pragma unroll
        for (int r = 0; r < 4; ++r) {
            int t = mf * 16 + lg * 4 + r;   // C/D: row=(lane>>4)*4+reg
            float mu = mu_s[t], rs = rs_s[t];
            float pp = 0.f;
            #pragma unroll
            for (int nf = 0; nf < 3; ++nf) {
                float x = rs * (acc[mf][nf][r] - mu * uf[nf]) + vbf[nf];
                float h = 0.5f * x * (1.f + erff(x * 0.70710678118f));  // exact GELU
                pp += h * w2f[nf];
            }
            ps[mf][r] = pp;
        }
    }
    #pragma unroll
    for (int m = 1; m < 16; m <<= 1)
        #pragma unroll
        for (int mf = 0; mf < 4; ++mf)
            #pragma unroll
            for (int r = 0; r < 4; ++r)
                ps[mf][r] += __shfl_xor(ps[mf][r], m, 64);
    if (col == 0) {
        #pragma unroll
        for (int mf = 0; mf < 4; ++mf)
            #pragma unroll
            for (int r = 0; r < 4; ++r)
                red2[w][mf * 16 + lg * 4 + r] = ps[mf][r];
    }
    __syncthreads();
    if (tid < 64) {
        float logit = red2[0][tid] + red2[1][tid] + red2[2][tid] + red2[3][tid] + b2_g[mod];
        out[(size_t)mod * 36864 + T0 + tid] = 1.f / (1.f + expf(-logit));
    }
}

// ---------- launch ----------
extern "C" void kernel_launch(void* const* d_in, const int* in_sizes, int n_in,
                              void* d_out, int out_size, void* d_ws, size_t ws_size,
                              hipStream_t stream)
{
    const float* f0  = (const float*)d_in[0];
    const float* f1  = (const float*)d_in[1];
    const float* f2  = (const float*)d_in[2];
    const float* lng = (const float*)d_in[3];
    const float* lnb = (const float*)d_in[4];
    const float* w1  = (const float*)d_in[5];
    const float* b1  = (const float*)d_in[6];
    const float* w2  = (const float*)d_in[7];
    const float* b2  = (const float*)d_in[8];
    float* out = (float*)d_out;

    char* ws = (char*)d_ws;
    unsigned short* w1f = (unsigned short*)ws;          // 884736 B
    float* u     = (float*)(ws + 884736);               // 2304 B
    float* vb    = (float*)(ws + 887040);               // 2304 B
    float* upart = (float*)(ws + 889344);               // 18432 B
    float* vpart = (float*)(ws + 907776);               // 18432 B (total ~926 KB)

    prep_partial<<<dim3(24), dim3(192), 0, stream>>>(w1, lng, lnb, upart, vpart);
    prep_combine<<<dim3(3),  dim3(192), 0, stream>>>(upart, vpart, b1, u, vb);
    prep_pack   <<<dim3(72), dim3(256), 0, stream>>>(w1, lng, w1f);
    fused_main  <<<dim3(3 * TPM), dim3(256), 0, stream>>>(f0, f1, f2, w1f, u, vb, w2, b2, out);
}